// Round 1
// baseline (1136.043 us; speedup 1.0000x reference)
//
#include <hip/hip_runtime.h>
#include <hip/hip_bf16.h>

// Problem constants (from setup_inputs): M=8 ensemble, B=4096 batch, I=2048 in, O=2048 out
#define M_ENS 8
#define BB    4096
#define KK    2048   // I (contraction dim)
#define OO    2048   // O

typedef __bf16 bf16x8 __attribute__((ext_vector_type(8)));
typedef float  f32x4  __attribute__((ext_vector_type(4)));

__device__ __forceinline__ unsigned short f2bf(float f) {
    __hip_bfloat16 h = __float2bfloat16(f);   // RNE
    return __builtin_bit_cast(unsigned short, h);
}

__device__ __forceinline__ float softplus_f(float x) {
    // numerically stable softplus: max(x,0) + log1p(exp(-|x|))
    return fmaxf(x, 0.f) + log1pf(__expf(-fabsf(x)));
}

// async global->LDS, 16B per lane, LDS dest = wave-uniform base + lane*16
typedef __attribute__((address_space(1))) unsigned int gu32;
typedef __attribute__((address_space(3))) unsigned int su32;
__device__ __forceinline__ void gload_lds16(const void* g, void* s) {
    __builtin_amdgcn_global_load_lds((gu32*)g, (su32*)s, 16, 0, 0);
}

// ---------------------------------------------------------------------------
// Kernel 1: wT[m][o][i] = bf16( mu[m][i][o] + softplus(rho[m][i][o])*eps[m][i][o] )
// grid (OO/256, KK/8, M): thread owns one o, 8 consecutive i -> one 16B store.
// ---------------------------------------------------------------------------
__global__ __launch_bounds__(256) void prep_w(const float* __restrict__ mu,
                                              const float* __restrict__ rho,
                                              const float* __restrict__ eps,
                                              unsigned short* __restrict__ wT) {
    const int o  = blockIdx.x * 256 + threadIdx.x;
    const int i0 = blockIdx.y * 8;
    const int m  = blockIdx.z;
    const size_t base = (size_t)m * KK * OO;

    union { unsigned short us[8]; uint4 q; } pk;
#pragma unroll
    for (int j = 0; j < 8; ++j) {
        const size_t idx = base + (size_t)(i0 + j) * OO + o;
        const float r  = rho[idx];
        const float sp = softplus_f(r);
        pk.us[j] = f2bf(fmaf(sp, eps[idx], mu[idx]));
    }
    *reinterpret_cast<uint4*>(&wT[base + (size_t)o * KK + i0]) = pk.q;
}

// ---------------------------------------------------------------------------
// Kernel 2: out[m] = x[m] (fp32 4096x2048) @ w[m] (bf16, stored transposed
//           [O][K]) + bias[m], 128x128 tile, BK=32, 16x16x32 bf16 MFMA.
// ---------------------------------------------------------------------------
#define BM  128
#define BN  128
#define BKT 32
#define LDA 40   // sA row stride in bf16 elements (+8 pad -> conflict-free b128)

__global__ __launch_bounds__(256) void gemm_kernel(const float* __restrict__ x,
                                                   const unsigned short* __restrict__ wT,
                                                   const float* __restrict__ bmu,
                                                   const float* __restrict__ brho,
                                                   const float* __restrict__ beps,
                                                   float* __restrict__ out) {
    // sB MUST be unpadded [BN][BKT] (global_load_lds order); XOR swizzle breaks conflicts
    __shared__ __align__(16) unsigned short sB[BN * BKT];   // 8 KB
    __shared__ __align__(16) unsigned short sA[BM * LDA];   // 10 KB
    __shared__ float sBias[BN];

    const int tid = threadIdx.x;
    const int w   = tid >> 6;      // wave 0..3
    const int l   = tid & 63;      // lane
    const int lr  = l & 15;        // MFMA row/col within frag
    const int lq  = l >> 4;        // MFMA quad
    const int n0   = blockIdx.x * BN;
    const int row0 = blockIdx.y * BM;
    const int m    = blockIdx.z;

    const float*          xm  = x   + (size_t)m * BB * KK;
    const unsigned short* wTm = wT  + (size_t)m * OO * KK;
    float*                om  = out + (size_t)m * BB * OO;

    // fused bias: b[o] = bmu + softplus(brho)*beps, for this block's 128 cols
    if (tid < BN) {
        const size_t bi = (size_t)m * OO + n0 + tid;
        sBias[tid] = fmaf(softplus_f(brho[bi]), beps[bi], bmu[bi]);
    }

    const int wm = w >> 1, wn = w & 1;   // wave tile: 64x64

    f32x4 acc[4][4];
#pragma unroll
    for (int a = 0; a < 4; ++a)
#pragma unroll
        for (int b = 0; b < 4; ++b)
#pragma unroll
            for (int j = 0; j < 4; ++j) acc[a][b][j] = 0.f;

    // --- B staging addresses (global_load_lds, 2 instrs/wave) ---
    // instr covers 16 rows (64B each); lane l -> row 16w + (l>>2), chunk l&3.
    // LDS slot (r,c) holds global chunk c ^ ((r>>1)&3)  [self-inverse swizzle]
    const int bswz = ((l & 3) ^ ((l >> 3) & 3)) * 8;   // global k-chunk offset (elems)
    const unsigned short* gB0 = wTm + (size_t)(n0 + 16 * w + (l >> 2)) * KK + bswz;
    const unsigned short* gB1 = gB0 + (size_t)64 * KK;
    unsigned short* sBw0 = sB + w * 512;          // bytes w*1024 (wave-uniform)
    unsigned short* sBw1 = sB + 2048 + w * 512;   // bytes 4096 + w*1024

    // --- A staging addresses (fp32 load -> bf16 -> ds_write) ---
    const int arow = tid >> 1, ahalf = tid & 1;   // row 0..127, 16-float half
    const float* gA = xm + (size_t)(row0 + arow) * KK + ahalf * 16;
    unsigned short* sAw = sA + arow * LDA + ahalf * 16;

    const int bq = (lq ^ ((lr >> 1) & 3)) * 8;    // read-side swizzled k-chunk (elems)

    for (int kt = 0; kt < KK / BKT; ++kt) {
        const int k0 = kt * BKT;

        // B tile: w^T rows [n0..n0+127], k chunk -> LDS (async DMA)
        gload_lds16(gB0 + k0, sBw0);
        gload_lds16(gB1 + k0, sBw1);

        // A tile: 16 fp32 per thread -> 16 bf16 -> 2x ds_write_b128
        const float4 f0 = *reinterpret_cast<const float4*>(gA + k0);
        const float4 f1 = *reinterpret_cast<const float4*>(gA + k0 + 4);
        const float4 f2 = *reinterpret_cast<const float4*>(gA + k0 + 8);
        const float4 f3 = *reinterpret_cast<const float4*>(gA + k0 + 12);
        union { unsigned short us[16]; uint4 q[2]; } pk;
        pk.us[0]  = f2bf(f0.x); pk.us[1]  = f2bf(f0.y); pk.us[2]  = f2bf(f0.z); pk.us[3]  = f2bf(f0.w);
        pk.us[4]  = f2bf(f1.x); pk.us[5]  = f2bf(f1.y); pk.us[6]  = f2bf(f1.z); pk.us[7]  = f2bf(f1.w);
        pk.us[8]  = f2bf(f2.x); pk.us[9]  = f2bf(f2.y); pk.us[10] = f2bf(f2.z); pk.us[11] = f2bf(f2.w);
        pk.us[12] = f2bf(f3.x); pk.us[13] = f2bf(f3.y); pk.us[14] = f2bf(f3.z); pk.us[15] = f2bf(f3.w);
        *reinterpret_cast<uint4*>(sAw)     = pk.q[0];
        *reinterpret_cast<uint4*>(sAw + 8) = pk.q[1];

        __syncthreads();   // drains vmcnt (global_load_lds) + lgkm

        bf16x8 af[4], bv[4];
#pragma unroll
        for (int a = 0; a < 4; ++a)
            af[a] = *reinterpret_cast<const bf16x8*>(&sA[(wm * 64 + a * 16 + lr) * LDA + lq * 8]);
#pragma unroll
        for (int b = 0; b < 4; ++b)
            bv[b] = *reinterpret_cast<const bf16x8*>(&sB[(wn * 64 + b * 16 + lr) * BKT + bq]);

#pragma unroll
        for (int a = 0; a < 4; ++a)
#pragma unroll
            for (int b = 0; b < 4; ++b)
                acc[a][b] = __builtin_amdgcn_mfma_f32_16x16x32_bf16(af[a], bv[b], acc[a][b], 0, 0, 0);

        __syncthreads();   // before next iteration overwrites LDS
    }

    // epilogue: C/D layout col = lane&15, row = quad*4 + reg
#pragma unroll
    for (int b = 0; b < 4; ++b) {
        const int col  = wn * 64 + b * 16 + lr;
        const float bias = sBias[col];
#pragma unroll
        for (int a = 0; a < 4; ++a) {
            const int rbase = row0 + wm * 64 + a * 16 + lq * 4;
            float* po = om + (size_t)rbase * OO + n0 + col;
#pragma unroll
            for (int j = 0; j < 4; ++j)
                po[(size_t)j * OO] = acc[a][b][j] + bias;
        }
    }
}

extern "C" void kernel_launch(void* const* d_in, const int* in_sizes, int n_in,
                              void* d_out, int out_size, void* d_ws, size_t ws_size,
                              hipStream_t stream) {
    const float* x    = (const float*)d_in[0];
    const float* wmu  = (const float*)d_in[1];
    const float* wrho = (const float*)d_in[2];
    const float* bmu  = (const float*)d_in[3];
    const float* brho = (const float*)d_in[4];
    const float* ew   = (const float*)d_in[5];
    const float* eb   = (const float*)d_in[6];
    float* out = (float*)d_out;

    unsigned short* wT = (unsigned short*)d_ws;  // 8*2048*2048*2 = 64 MiB

    prep_w<<<dim3(OO / 256, KK / 8, M_ENS), 256, 0, stream>>>(wmu, wrho, ew, wT);
    gemm_kernel<<<dim3(OO / BN, BB / BM, M_ENS), 256, 0, stream>>>(x, wT, bmu, brho, eb, out);
}